// Round 4
// baseline (373.871 us; speedup 1.0000x reference)
//
#include <hip/hip_runtime.h>
#include <math.h>

// VectorExpansion: out[l, p, n] = sin(pi*x*n)/max(r,eps) * fc(r) * sqrt(2/rc) * x^l
// x = r/rc, rc=5, n=1..8, l=0..3.  fp32 in / fp32 out (verified R3, absmax 4.9e-4).
//
// R4 changes vs R3 (365 us, ~0.9 TB/s effective, 7x off write-roofline):
//  - sincosf -> raw v_sin/v_cos: pi*x in [0,pi) needs NO range reduction;
//    v_sin_f32(y)=sin(2*pi*y) so sin(pi*x)=v_sin(x/2). Kills the libm call.
//  - branchless cutoff (pref=0 outside) -> no divergent dual store paths.
//  - cells (S*9 floats) + structure_offsets (S ints) staged in LDS;
//    sC[9s+k]: 9 coprime 32 -> bank-conflict-free across lanes.

#define RC_INV 0.2f
#define NORM 0.6324555320336759f  /* sqrt(2/5) */

__global__ __launch_bounds__(256) void ve_kernel(
    const float* __restrict__ positions,        // [N,3] fp32
    const float* __restrict__ cells,            // [S,3,3] fp32
    const int* __restrict__ cell_shifts,        // [P,3]
    const int* __restrict__ pairs,              // [P,2]
    const int* __restrict__ structure_pairs,    // [P]
    const int* __restrict__ structure_offsets,  // [S]
    float* __restrict__ out,                    // [4,P,8] fp32
    int P, int S)
{
    extern __shared__ float smem[];             // [S*9] cells, then [S] int offsets
    float* sC  = smem;
    int*   sOf = (int*)(smem + 9 * S);
    for (int t = threadIdx.x; t < 9 * S; t += blockDim.x) sC[t] = cells[t];
    for (int t = threadIdx.x; t < S;     t += blockDim.x) sOf[t] = structure_offsets[t];
    __syncthreads();

    const int p = blockIdx.x * blockDim.x + threadIdx.x;
    if (p >= P) return;

    const int s   = structure_pairs[p];
    const int off = sOf[s];
    const int2 pr = ((const int2*)pairs)[p];
    const int ia = off + pr.x;
    const int ja = off + pr.y;

    const float shx = (float)cell_shifts[3*p + 0];
    const float shy = (float)cell_shifts[3*p + 1];
    const float shz = (float)cell_shifts[3*p + 2];

    const float* C = sC + 9*s;                  // row-major [c][d]
    const float vx = positions[3*ja+0] - positions[3*ia+0] + shx*C[0] + shy*C[3] + shz*C[6];
    const float vy = positions[3*ja+1] - positions[3*ia+1] + shx*C[1] + shy*C[4] + shz*C[7];
    const float vz = positions[3*ja+2] - positions[3*ia+2] + shx*C[2] + shy*C[5] + shz*C[8];

    const float d2 = vx*vx + vy*vy + vz*vz + 1e-12f;
    const float r  = __builtin_amdgcn_sqrtf(d2);
    const float x  = r * RC_INV;

    // sin(pi*x), cos(pi*x) via HW trig (arg in revolutions): y = x/2, no range reduction
    const float s1 = __builtin_amdgcn_sinf(0.5f * x);
    const float c1 = __builtin_amdgcn_cosf(0.5f * x);
    const float fc = 0.5f * (c1 + 1.0f);
    // branchless cutoff: zero prefactor outside r_cut -> all 32 outputs exactly 0
    const float pref = (x < 1.0f) ? fc * NORM * __builtin_amdgcn_rcpf(r) : 0.0f;

    // sin(n*pi*x) by Chebyshev recurrence: s_{n+1} = 2*cos(pi*x)*s_n - s_{n-1}
    float b[8];
    {
        float sm1 = 0.0f, sn = s1;
        const float twoc = 2.0f * c1;
        #pragma unroll
        for (int n = 0; n < 8; ++n) {
            b[n] = pref * sn;
            const float nxt = twoc * sn - sm1;
            sm1 = sn; sn = nxt;
        }
    }

    // out flat (l,p,n) = l*P*8 + p*8 + n  ->  float4 slot (l*P+p)*2 + {0,1}
    float4* out4 = (float4*)out;
    float xl = 1.0f;
    #pragma unroll
    for (int l = 0; l < 4; ++l) {
        const long long base = 2LL * (1LL*l*P + p);
        out4[base + 0] = make_float4(b[0]*xl, b[1]*xl, b[2]*xl, b[3]*xl);
        out4[base + 1] = make_float4(b[4]*xl, b[5]*xl, b[6]*xl, b[7]*xl);
        xl *= x;
    }
}

extern "C" void kernel_launch(void* const* d_in, const int* in_sizes, int n_in,
                              void* d_out, int out_size, void* d_ws, size_t ws_size,
                              hipStream_t stream) {
    const float* positions         = (const float*)d_in[0];
    const float* cells             = (const float*)d_in[1];
    const int*   cell_shifts       = (const int*)d_in[3];
    const int*   pairs             = (const int*)d_in[5];
    const int*   structure_pairs   = (const int*)d_in[7];
    const int*   structure_offsets = (const int*)d_in[8];
    float*       out               = (float*)d_out;

    const int P = in_sizes[7];          // structure_pairs is [P]
    const int S = in_sizes[8];          // structure_offsets is [S]
    const int block = 256;
    const int grid = (P + block - 1) / block;
    const size_t shmem = (size_t)(9 * S) * sizeof(float) + (size_t)S * sizeof(int);
    ve_kernel<<<grid, block, shmem, stream>>>(positions, cells, cell_shifts, pairs,
                                              structure_pairs, structure_offsets, out, P, S);
}

// Round 5
// 331.912 us; speedup vs baseline: 1.1264x; 1.1264x over previous
//
#include <hip/hip_runtime.h>
#include <math.h>

// VectorExpansion: out[l, p, n] = sin(pi*x*n)/max(r,eps) * fc(r) * sqrt(2/rc) * x^l
// x = r/rc, rc=5, n=1..8, l=0..3.  fp32 in / fp32 out (verified R3).
//
// R5 structure (post-mortem R4: single-pass kernel ~150us, 3x off the ~50us
// traffic roofline; 97% of pairs are outside cutoff -> all-zero rows):
//  kernel 1: pure zero-fill of d_out (268 MB). Harness's own fill kernels
//            prove a trivial store-only kernel runs at ~6.3 TB/s (~43us).
//  kernel 2: sparse pair pass — read pair data, compute r, and ONLY the ~3%
//            inside-cutoff lanes do trig + stores (~8 MB scattered writes).

#define RC_INV 0.2f
#define NORM 0.6324555320336759f  /* sqrt(2/5) */

__global__ __launch_bounds__(256) void zero_fill4(float4* __restrict__ out, int n4) {
    const int i = blockIdx.x * blockDim.x + threadIdx.x;
    if (i < n4) out[i] = make_float4(0.f, 0.f, 0.f, 0.f);
}

__global__ __launch_bounds__(256) void ve_sparse(
    const float* __restrict__ positions,        // [N,3] fp32
    const float* __restrict__ cells,            // [S,3,3] fp32
    const int* __restrict__ cell_shifts,        // [P,3]
    const int* __restrict__ pairs,              // [P,2]
    const int* __restrict__ structure_pairs,    // [P]
    const int* __restrict__ structure_offsets,  // [S]
    float* __restrict__ out,                    // [4,P,8] fp32 (pre-zeroed)
    int P)
{
    const int p = blockIdx.x * blockDim.x + threadIdx.x;
    if (p >= P) return;

    const int s   = structure_pairs[p];
    const int off = structure_offsets[s];       // S=32 table, L1-resident
    const int2 pr = ((const int2*)pairs)[p];
    const int ia = off + pr.x;
    const int ja = off + pr.y;

    const float shx = (float)cell_shifts[3*p + 0];
    const float shy = (float)cell_shifts[3*p + 1];
    const float shz = (float)cell_shifts[3*p + 2];

    const float* C = cells + 9*s;               // row-major [c][d], L1-resident
    const float vx = positions[3*ja+0] - positions[3*ia+0] + shx*C[0] + shy*C[3] + shz*C[6];
    const float vy = positions[3*ja+1] - positions[3*ia+1] + shx*C[1] + shy*C[4] + shz*C[7];
    const float vz = positions[3*ja+2] - positions[3*ia+2] + shx*C[2] + shy*C[5] + shz*C[8];

    const float d2 = vx*vx + vy*vy + vz*vz + 1e-12f;
    const float r  = __builtin_amdgcn_sqrtf(d2);
    const float x  = r * RC_INV;

    if (x >= 1.0f) return;                      // fc==0 -> row already zeroed by fill

    // sin(pi*x), cos(pi*x) via HW trig (arg in revolutions; pi*x in [0,pi) needs
    // no range reduction): sin(pi*x) = v_sin(x/2)
    const float s1 = __builtin_amdgcn_sinf(0.5f * x);
    const float c1 = __builtin_amdgcn_cosf(0.5f * x);
    const float fc = 0.5f * (c1 + 1.0f);
    const float pref = fc * NORM * __builtin_amdgcn_rcpf(r);

    // sin(n*pi*x) by Chebyshev recurrence: s_{n+1} = 2*cos(pi*x)*s_n - s_{n-1}
    float b[8];
    {
        float sm1 = 0.0f, sn = s1;
        const float twoc = 2.0f * c1;
        #pragma unroll
        for (int n = 0; n < 8; ++n) {
            b[n] = pref * sn;
            const float nxt = twoc * sn - sm1;
            sm1 = sn; sn = nxt;
        }
    }

    // out flat (l,p,n) = l*P*8 + p*8 + n  ->  float4 slot (l*P+p)*2 + {0,1}
    float4* out4 = (float4*)out;
    float xl = 1.0f;
    #pragma unroll
    for (int l = 0; l < 4; ++l) {
        const long long base = 2LL * (1LL*l*P + p);
        out4[base + 0] = make_float4(b[0]*xl, b[1]*xl, b[2]*xl, b[3]*xl);
        out4[base + 1] = make_float4(b[4]*xl, b[5]*xl, b[6]*xl, b[7]*xl);
        xl *= x;
    }
}

extern "C" void kernel_launch(void* const* d_in, const int* in_sizes, int n_in,
                              void* d_out, int out_size, void* d_ws, size_t ws_size,
                              hipStream_t stream) {
    const float* positions         = (const float*)d_in[0];
    const float* cells             = (const float*)d_in[1];
    const int*   cell_shifts       = (const int*)d_in[3];
    const int*   pairs             = (const int*)d_in[5];
    const int*   structure_pairs   = (const int*)d_in[7];
    const int*   structure_offsets = (const int*)d_in[8];
    float*       out               = (float*)d_out;

    const int P = in_sizes[7];          // structure_pairs is [P]
    const int block = 256;

    const int n4 = out_size / 4;        // out_size = 4*P*8, divisible by 4
    zero_fill4<<<(n4 + block - 1) / block, block, 0, stream>>>((float4*)out, n4);

    ve_sparse<<<(P + block - 1) / block, block, 0, stream>>>(
        positions, cells, cell_shifts, pairs,
        structure_pairs, structure_offsets, out, P);
}